// Round 11
// baseline (271.046 us; speedup 1.0000x reference)
//
#include <hip/hip_runtime.h>
#include <math.h>

// Problem constants (from reference)
#define HH 256
#define WW 256
#define CC 32
#define SS 32
#define NRAYS 32768            // N*R = 2*16384
#define RPB 8                  // rays per block
#define TEXOFF 256             // byte offset of HWC texture in d_ws

// LDS pool layout (bytes, all 16-aligned)
#define FXB_OFF 0              // 256 rows x 80 B: gather-in ch c @hw c; rgb-out ch c @hw c+1
#define SIG_OFF 20480          // f32[256] raw sigma
#define WST_OFF 21504          // w1t 4096 B | w2t 6144 B; aliased by hb after frag load
#define W2T_OFF 25600
#define ALP_OFF 31744          // f32[256]: per-interval alpha -> 0.5*alpha*T weights
#define POOLSZ  32768
// hb (per-wave h buffer, 16 rows x 144 B) aliases WST: wave w at WST_OFF + w*2304

typedef __attribute__((ext_vector_type(8))) short short8;   // 8 bf16
typedef __attribute__((ext_vector_type(4))) float f32x4;

__device__ __forceinline__ f32x4 mfma16(short8 a, short8 b, f32x4 c) {
    return __builtin_amdgcn_mfma_f32_16x16x32_bf16(a, b, c, 0, 0, 0);
}

// ---------- helpers ----------
__device__ __forceinline__ float bf2f(unsigned short u) {
    union { unsigned int ui; float f; } v; v.ui = ((unsigned int)u) << 16; return v.f;
}
__device__ __forceinline__ unsigned short f2bf(float f) {
    union { float f; unsigned int u; } v; v.f = f;
    unsigned int u = v.u;
    unsigned int r = u + 0x7fffu + ((u >> 16) & 1u);   // RNE
    return (unsigned short)(r >> 16);
}
// pack 2 f32 -> 2 bf16 in one dword (hw instr when available)
__device__ __forceinline__ unsigned int pk_bf16(float a, float b) {
#if defined(__has_builtin)
#if __has_builtin(__builtin_amdgcn_cvt_pk_bf16_f32)
    auto r = __builtin_amdgcn_cvt_pk_bf16_f32(a, b);
    unsigned int u; __builtin_memcpy(&u, &r, 4); return u;
#else
    return (unsigned int)f2bf(a) | ((unsigned int)f2bf(b) << 16);
#endif
#else
    return (unsigned int)f2bf(a) | ((unsigned int)f2bf(b) << 16);
#endif
}
__device__ __forceinline__ int iclamp(int x, int lo, int hi) {
    return x < lo ? lo : (x > hi ? hi : x);
}
__device__ __forceinline__ float softplus_f(float z) {       // precise (fallback)
    return fmaxf(z, 0.f) + log1pf(expf(-fabsf(z)));
}
__device__ __forceinline__ float softplus_fast(float z) {
    return fmaxf(z, 0.f) + __logf(1.0f + __expf(-fabsf(z)));
}
__device__ __forceinline__ float sigmoid_fast(float z) {
    return __builtin_amdgcn_rcpf(1.0f + __expf(-z));
}

template<bool F32>
__device__ __forceinline__ float ldv(const void* p, size_t i) {
    if (F32) return ((const float*)p)[i];
    else     return bf2f(((const unsigned short*)p)[i]);
}

// ---------- dtype detection: |ray_origin| == 2.7 (by construction) ----------
__global__ void detect_dtype(const void* __restrict__ rayo, int* __restrict__ flag) {
    const int t = threadIdx.x;
    float sf = 0.f, sb = 0.f;
    if (t < 8) {
        const float* f = (const float*)rayo;
        const unsigned short* u = (const unsigned short*)rayo;
        const float a = f[3 * t], b = f[3 * t + 1], c = f[3 * t + 2];
        const float nf = a * a + b * b + c * c;
        sf = fminf(fabsf(nf - 7.29f), 1e3f);            // fminf(NaN,x)=x -> NaN-safe
        const float x = bf2f(u[3 * t]), y = bf2f(u[3 * t + 1]), z = bf2f(u[3 * t + 2]);
        const float nb = x * x + y * y + z * z;
        sb = fminf(fabsf(nb - 7.29f), 1e3f);
    }
    sf += __shfl_down(sf, 4); sb += __shfl_down(sb, 4);
    sf += __shfl_down(sf, 2); sb += __shfl_down(sb, 2);
    sf += __shfl_down(sf, 1); sb += __shfl_down(sb, 1);
    if (t == 0 && blockIdx.x == 0) *flag = (sf < sb) ? 1 : 0;   // 1 = float32 inputs
}

// ---------- CHW -> HWC transpose, vectorized both sides ----------
__global__ __launch_bounds__(1024) void transpose_tex(
    const void* __restrict__ vol, void* __restrict__ tex, const int* __restrict__ flag) {
    __shared__ __align__(16) float          tf[32][129];
    __shared__ __align__(16) unsigned short tb[32][129];
    const int l = threadIdx.x;
    const int tx = l & 31, ty = l >> 5;    // phase 1: c = ty, w-quad = tx
    const int wq = l >> 3, cq = l & 7;     // phase 2: w = w0+wq, c-quad = cq
    const int w0 = blockIdx.x * 128;
    const int h  = blockIdx.y;
    const int img = blockIdx.z;
    const size_t srcE = (((size_t)img * CC + ty) * HH + h) * WW + w0 + 4 * tx;
    const size_t dstE = (((size_t)img * HH + h) * WW + (w0 + wq)) * CC + 4 * cq;
    if (*flag) {
        const float4 v = *(const float4*)((const float*)vol + srcE);
        tf[ty][4 * tx + 0] = v.x; tf[ty][4 * tx + 1] = v.y;
        tf[ty][4 * tx + 2] = v.z; tf[ty][4 * tx + 3] = v.w;
        __syncthreads();
        float4 o;
        o.x = tf[4 * cq + 0][wq]; o.y = tf[4 * cq + 1][wq];
        o.z = tf[4 * cq + 2][wq]; o.w = tf[4 * cq + 3][wq];
        *(float4*)((float*)tex + dstE) = o;
    } else {
        const ushort4 v = *(const ushort4*)((const unsigned short*)vol + srcE);
        tb[ty][4 * tx + 0] = v.x; tb[ty][4 * tx + 1] = v.y;
        tb[ty][4 * tx + 2] = v.z; tb[ty][4 * tx + 3] = v.w;
        __syncthreads();
        ushort4 o;
        o.x = tb[4 * cq + 0][wq]; o.y = tb[4 * cq + 1][wq];
        o.z = tb[4 * cq + 2][wq]; o.w = tb[4 * cq + 3][wq];
        *(ushort4*)((unsigned short*)tex + dstE) = o;
    }
}

// ================= fast path: float4 gather + MFMA MLP + split marcher =================
template<bool F32>
__device__ void render_mfma_body(
    const void* __restrict__ tex,   // [6][256][256][32] HWC
    const void* __restrict__ rayo, const void* __restrict__ rayd,
    const void* __restrict__ w1b, const void* __restrict__ b1b,
    const void* __restrict__ w2b, const void* __restrict__ b2b,
    void* __restrict__ outp, char* __restrict__ pool)
{
    const int t = threadIdx.x;
    unsigned short* fxB = (unsigned short*)(pool + FXB_OFF);   // stride 40 ushort/row
    float* sigL = (float*)(pool + SIG_OFF);
    unsigned short* w1t = (unsigned short*)(pool + WST_OFF);   // [n<64][k<32]
    unsigned short* w2t = (unsigned short*)(pool + W2T_OFF);   // [n<48][k<64]
    float* aL = (float*)(pool + ALP_OFF);                      // alpha -> weights

    // ---- stage weights (transposed, bf16) ----
    for (int i = t; i < 2048; i += 256) {        // w1 [32][64]: i = k*64+n
        const int k = i >> 6, n = i & 63;
        w1t[n * 32 + k] = f2bf(ldv<F32>(w1b, i));
    }
    for (int i = t; i < 3072; i += 256) {        // w2 [64][33] -> w2t [48][64]
        const int n = i >> 6, k = i & 63;
        w2t[n * 64 + k] = (n < 33) ? f2bf(ldv<F32>(w2b, (size_t)k * 33 + n)) : (unsigned short)0;
    }
    __syncthreads();

    // ---- gather: 8-lane sub-group per (ray, sample-subset); lane = 4 channels ----
    {
        const int rl = t >> 5;                 // ray in block
        const int L  = t & 31;
        const int c4 = L & 7;                  // channel quad: ch 4*c4..4*c4+3
        const int sub = L >> 3;                // sample subset 0..3
        const int gray = blockIdx.x * RPB + rl;
        const int n = gray >> 14;
        const size_t rb = (size_t)gray * 3;
        const float ox = ldv<F32>(rayo, rb), oy = ldv<F32>(rayo, rb + 1), oz = ldv<F32>(rayo, rb + 2);
        const float dx = ldv<F32>(rayd, rb), dy = ldv<F32>(rayd, rb + 1), dz = ldv<F32>(rayd, rb + 2);

        #pragma unroll 2
        for (int k = 0; k < 8; ++k) {
            const int s = sub * 8 + k;
            const float d = 2.25f + 1.05f * ((s + 0.5f) * (1.0f / 32.0f));
            const float x = (ox + d * dx) * 2.0f;
            const float y = (oy + d * dy) * 2.0f;
            const float z = (oz + d * dz) * 2.0f;
            float a0[4] = {0.f, 0.f, 0.f, 0.f};
            float a1[4] = {0.f, 0.f, 0.f, 0.f};
            float a2[4] = {0.f, 0.f, 0.f, 0.f};
            #pragma unroll
            for (int p = 0; p < 3; p++) {
                // p0:(x,y)  p1:(y,z)  p2:(x,z)
                const float u = (p == 0) ? x : ((p == 1) ? y : x);
                const float v = (p == 0) ? y : z;
                const float ixf = fmaf(u, 127.5f, 127.5f);
                const float iyf = fmaf(v, 127.5f, 127.5f);
                const float ix0f = floorf(ixf), iy0f = floorf(iyf);
                const float wx1 = ixf - ix0f, wy1 = iyf - iy0f;
                const float wx0 = 1.f - wx1,  wy0 = 1.f - wy1;
                const int ix0 = iclamp((int)ix0f, 0, 255);
                const int ix1 = iclamp((int)ix0f + 1, 0, 255);
                const int iy0 = iclamp((int)iy0f, 0, 255);
                const int iy1 = iclamp((int)iy0f + 1, 0, 255);
                const float w00 = wx0 * wy0, w01 = wx1 * wy0, w10 = wx0 * wy1, w11 = wx1 * wy1;
                const unsigned int pb4 = (unsigned int)(n * 3 + p) * (HH * WW * CC / 4);
                float v00[4], v01[4], v10[4], v11[4];
                if (F32) {
                    const float4* tx4 = (const float4*)tex;
                    const float4 q00 = tx4[pb4 + ((unsigned int)(iy0 * WW + ix0) << 3) + c4];
                    const float4 q01 = tx4[pb4 + ((unsigned int)(iy0 * WW + ix1) << 3) + c4];
                    const float4 q10 = tx4[pb4 + ((unsigned int)(iy1 * WW + ix0) << 3) + c4];
                    const float4 q11 = tx4[pb4 + ((unsigned int)(iy1 * WW + ix1) << 3) + c4];
                    v00[0] = q00.x; v00[1] = q00.y; v00[2] = q00.z; v00[3] = q00.w;
                    v01[0] = q01.x; v01[1] = q01.y; v01[2] = q01.z; v01[3] = q01.w;
                    v10[0] = q10.x; v10[1] = q10.y; v10[2] = q10.z; v10[3] = q10.w;
                    v11[0] = q11.x; v11[1] = q11.y; v11[2] = q11.z; v11[3] = q11.w;
                } else {
                    #pragma unroll
                    for (int i = 0; i < 4; i++) {
                        const size_t e = (size_t)pb4 * 4 + 4 * c4 + i;
                        v00[i] = ldv<false>(tex, e + ((size_t)(iy0 * WW + ix0) << 5));
                        v01[i] = ldv<false>(tex, e + ((size_t)(iy0 * WW + ix1) << 5));
                        v10[i] = ldv<false>(tex, e + ((size_t)(iy1 * WW + ix0) << 5));
                        v11[i] = ldv<false>(tex, e + ((size_t)(iy1 * WW + ix1) << 5));
                    }
                }
                #pragma unroll
                for (int i = 0; i < 4; i++) {
                    float acc = w00 * v00[i];
                    acc = fmaf(w01, v01[i], acc);
                    acc = fmaf(w10, v10[i], acc);
                    acc = fmaf(w11, v11[i], acc);
                    if (p == 0) a0[i] = acc; else if (p == 1) a1[i] = acc; else a2[i] = acc;
                }
            }
            // pack 4 bf16 channels (hw pack), single 8-B LDS write
            uint2 pk;
            pk.x = pk_bf16((a0[0] + a1[0] + a2[0]) * (1.0f / 3.0f),
                           (a0[1] + a1[1] + a2[1]) * (1.0f / 3.0f));
            pk.y = pk_bf16((a0[2] + a1[2] + a2[2]) * (1.0f / 3.0f),
                           (a0[3] + a1[3] + a2[3]) * (1.0f / 3.0f));
            *(uint2*)(pool + FXB_OFF + (rl * 32 + s) * 80 + c4 * 8) = pk;
        }
    }

    // ---- load B fragments to registers (w1t/w2t LDS dies after this) ----
    const int w = t >> 6;
    const int lane = t & 63;
    const int l16 = lane & 15, quad = lane >> 4;
    const bool evenl = (l16 & 1) == 0;

    short8 b1f[4];
    #pragma unroll
    for (int nt = 0; nt < 4; nt++)
        b1f[nt] = *(const short8*)(pool + WST_OFF + (nt * 16 + l16) * 64 + quad * 16);
    short8 b2f[3][2];
    #pragma unroll
    for (int nt = 0; nt < 3; nt++)
        #pragma unroll
        for (int ks = 0; ks < 2; ks++)
            b2f[nt][ks] = *(const short8*)(pool + W2T_OFF + (nt * 16 + l16) * 128 + ks * 64 + quad * 16);
    float bb1[4], bb2[3];
    #pragma unroll
    for (int nt = 0; nt < 4; nt++) bb1[nt] = ldv<F32>(b1b, nt * 16 + l16);
    #pragma unroll
    for (int nt = 0; nt < 3; nt++) {
        const int n2 = nt * 16 + l16;
        bb2[nt] = (n2 < 33) ? ldv<F32>(b2b, n2) : 0.f;
    }
    __syncthreads();   // fxB ready; all waves done reading w1t/w2t (hb aliases it)

    // ---- MFMA MLP: wave w owns sample rows [64w, 64w+64) ----
    {
        char* hb = pool + WST_OFF + w * 2304;    // 16 rows x 144 B
        #pragma unroll 1
        for (int mt = 0; mt < 4; mt++) {
            const int rbase = w * 64 + mt * 16;
            const short8 a1 = *(const short8*)(pool + FXB_OFF + (rbase + l16) * 80 + quad * 16);
            #pragma unroll
            for (int nt = 0; nt < 4; nt++) {
                f32x4 hc = { bb1[nt], bb1[nt], bb1[nt], bb1[nt] };
                hc = mfma16(a1, b1f[nt], hc);
                #pragma unroll
                for (int r = 0; r < 4; r++) {
                    const float hv = softplus_fast(hc[r]);
                    const float hn = __shfl_xor(hv, 1);
                    if (evenl)   // paired dword store: conflict-free
                        *(unsigned int*)(hb + (quad * 4 + r) * 144 + (nt * 16 + l16) * 2)
                            = pk_bf16(hv, hn);
                }
            }
            const short8 a2k0 = *(const short8*)(hb + l16 * 144 + quad * 16);
            const short8 a2k1 = *(const short8*)(hb + l16 * 144 + 64 + quad * 16);
            #pragma unroll
            for (int nt = 0; nt < 3; nt++) {
                f32x4 o = { bb2[nt], bb2[nt], bb2[nt], bb2[nt] };
                o = mfma16(a2k0, b2f[nt][0], o);
                o = mfma16(a2k1, b2f[nt][1], o);
                #pragma unroll
                for (int r = 0; r < 4; r++) {
                    const int row = rbase + quad * 4 + r;
                    // rgb stored at halfword slot nt*16+l16 (= channel+1); marcher reads c+1
                    const float sg = sigmoid_fast(o[r]);
                    const float val = fmaf(sg, 1.002f, -0.001f);
                    const float vn = __shfl_xor(val, 1);
                    if (nt == 0 && l16 == 0) sigL[row] = o[r];      // raw sigma
                    if (evenl && (nt < 2 || l16 == 0))
                        *(unsigned int*)(pool + FXB_OFF + row * 80 + (nt * 16 + l16) * 2)
                            = pk_bf16(val, vn);
                }
            }
        }
    }
    __syncthreads();

    // ---- marcher phase 1: thread t = (ray rl, interval sm) computes alpha once ----
    {
        const int rl = t >> 5, sm = t & 31;
        if (sm < 31) {
            const float sp = sigL[rl * 32 + sm];
            const float sn = sigL[rl * 32 + sm + 1];
            const float m = 0.5f * (sp + sn) - 1.0f;
            const float dens = fmaxf(m, 0.f) + __logf(1.0f + __expf(-fabsf(m)));
            aL[rl * 32 + sm] = 1.0f - __expf(-(1.05f / 32.0f) * dens);
        }
    }
    __syncthreads();

    // ---- marcher phase 2: one lane per ray does the serial T-scan -> 0.5*alpha*T ----
    {
        const int rl = t >> 5, sm = t & 31;
        if (sm == 0) {
            float T = 1.0f;
            #pragma unroll
            for (int j = 0; j < 31; j++) {
                const float a = aL[rl * 32 + j];
                aL[rl * 32 + j] = (a * T) * 0.5f;
                T *= (1.0f - a + 1e-10f);
            }
        }
    }
    __syncthreads();

    // ---- marcher phase 3: pure FMA channel walk (rgb ch c at slot c+1) ----
    {
        const int rl = t >> 5, c = t & 31;
        const int gr2 = blockIdx.x * RPB + rl;
        float acc = 0.0f;
        float rp = bf2f(fxB[(rl * 32 + 0) * 40 + (c + 1)]);
        #pragma unroll 4
        for (int sm = 0; sm < 31; sm++) {
            const float rn = bf2f(fxB[(rl * 32 + sm + 1) * 40 + (c + 1)]);
            acc = fmaf(aL[rl * 32 + sm], rp + rn, acc);
            rp = rn;
        }
        const size_t oidx = (size_t)gr2 * 32 + c;
        if (F32) ((float*)outp)[oidx] = acc;
        else     ((unsigned short*)outp)[oidx] = f2bf(acc);
    }
}

__global__ __launch_bounds__(256, 4) void render_fast(
    const void* __restrict__ tex, const void* __restrict__ rayo,
    const void* __restrict__ rayd, const void* __restrict__ w1b,
    const void* __restrict__ b1b, const void* __restrict__ w2b,
    const void* __restrict__ b2b, void* __restrict__ outp,
    const int* __restrict__ flag)
{
    __shared__ __align__(16) char pool[POOLSZ];
    if (*flag) render_mfma_body<true >(tex, rayo, rayd, w1b, b1b, w2b, b2b, outp, pool);
    else       render_mfma_body<false>(tex, rayo, rayd, w1b, b1b, w2b, b2b, outp, pool);
}

// ================= no-workspace fallback (round-3 verified) =================
template<bool F32>
__device__ __forceinline__ void render_body(
    const void* __restrict__ vol, const void* __restrict__ rayo,
    const void* __restrict__ rayd, const void* __restrict__ w1b,
    const void* __restrict__ b1b, const void* __restrict__ w2b,
    const void* __restrict__ b2b, void* __restrict__ outp,
    float* wsm, float (*rgbL)[SS][33], float (*sigL)[SS])
{
    const int t = threadIdx.x;
    for (int i = t; i < 4257; i += 256) {
        float v;
        if (i < 2048)       v = ldv<F32>(w1b, i);
        else if (i < 2112)  v = ldv<F32>(b1b, i - 2048);
        else if (i < 4224)  v = ldv<F32>(w2b, i - 2112);
        else                v = ldv<F32>(b2b, i - 4224);
        wsm[i] = v;
    }
    __syncthreads();

    const int rl = t >> 5;
    const int s  = t & 31;
    const int gray = blockIdx.x * RPB + rl;
    const int n = gray >> 14;

    const size_t rbase = (size_t)gray * 3;
    const float ox = ldv<F32>(rayo, rbase), oy = ldv<F32>(rayo, rbase + 1), oz = ldv<F32>(rayo, rbase + 2);
    const float dx = ldv<F32>(rayd, rbase), dy = ldv<F32>(rayd, rbase + 1), dz = ldv<F32>(rayd, rbase + 2);
    const float d = 2.25f + 1.05f * ((s + 0.5f) * (1.0f / 32.0f));
    const float x = (ox + d * dx) * 2.0f;
    const float y = (oy + d * dy) * 2.0f;
    const float z = (oz + d * dz) * 2.0f;

    float fx[32];
    #pragma unroll
    for (int c = 0; c < 32; c++) fx[c] = 0.f;

    #pragma unroll
    for (int p = 0; p < 3; p++) {
        const float u = (p == 0) ? x : ((p == 1) ? y : x);
        const float v = (p == 0) ? y : z;
        const float ixf = fmaf(u, 127.5f, 127.5f);
        const float iyf = fmaf(v, 127.5f, 127.5f);
        const float ix0f = floorf(ixf), iy0f = floorf(iyf);
        const float wx1 = ixf - ix0f, wy1 = iyf - iy0f;
        const float wx0 = 1.f - wx1,  wy0 = 1.f - wy1;
        const int ix0 = iclamp((int)ix0f, 0, 255);
        const int ix1 = iclamp((int)ix0f + 1, 0, 255);
        const int iy0 = iclamp((int)iy0f, 0, 255);
        const int iy1 = iclamp((int)iy0f + 1, 0, 255);
        const float wnw = wx0 * wy0, wne = wx1 * wy0, wsw = wx0 * wy1, wse = wx1 * wy1;
        const int i00 = iy0 * WW + ix0, i01 = iy0 * WW + ix1;
        const int i10 = iy1 * WW + ix0, i11 = iy1 * WW + ix1;
        const size_t pb = (size_t)(n * 3 + p) * CC * HH * WW;
        #pragma unroll
        for (int c = 0; c < 32; c++) {
            const size_t cb = pb + (size_t)c * (HH * WW);
            fx[c] += wnw * ldv<F32>(vol, cb + i00) + wne * ldv<F32>(vol, cb + i01)
                   + wsw * ldv<F32>(vol, cb + i10) + wse * ldv<F32>(vol, cb + i11);
        }
    }
    #pragma unroll
    for (int c = 0; c < 32; c++) fx[c] *= (1.0f / 3.0f);

    const float* W1 = wsm;
    const float* B1 = wsm + 2048;
    const float* W2 = wsm + 2112;
    const float* B2 = wsm + 4224;

    float h[64];
    #pragma unroll
    for (int j = 0; j < 64; j++) h[j] = B1[j];
    #pragma unroll
    for (int c = 0; c < 32; c++) {
        const float f = fx[c];
        #pragma unroll
        for (int j = 0; j < 64; j++) h[j] = fmaf(f, W1[c * 64 + j], h[j]);
    }
    #pragma unroll
    for (int j = 0; j < 64; j++) h[j] = softplus_f(h[j]);

    #pragma unroll 1
    for (int k = 0; k < 33; k++) {
        float zz = B2[k];
        #pragma unroll
        for (int j = 0; j < 64; j++) zz = fmaf(h[j], W2[j * 33 + k], zz);
        if (k == 0) sigL[rl][s] = zz;
        else {
            const float sg = 1.0f / (1.0f + expf(-zz));
            rgbL[rl][s][k - 1] = fmaf(sg, 1.002f, -0.001f);
        }
    }
    __syncthreads();

    const int c = t & 31;
    const float delta = 1.05f / 32.0f;
    float T = 1.0f, acc = 0.0f;
    float sig_prev = sigL[rl][0];
    float rgb_prev = rgbL[rl][0][c];
    #pragma unroll 1
    for (int sm = 0; sm < 31; sm++) {
        const float sig_next = sigL[rl][sm + 1];
        const float rgb_next = rgbL[rl][sm + 1][c];
        const float dens = softplus_f(0.5f * (sig_prev + sig_next) - 1.0f);
        const float alpha = 1.0f - expf(-delta * dens);
        acc += alpha * T * 0.5f * (rgb_prev + rgb_next);
        T *= (1.0f - alpha + 1e-10f);
        sig_prev = sig_next;
        rgb_prev = rgb_next;
    }
    const size_t oidx = (size_t)gray * 32 + c;
    if (F32) ((float*)outp)[oidx] = acc;
    else     ((unsigned short*)outp)[oidx] = f2bf(acc);
}

__global__ __launch_bounds__(256) void render_any(
    const void* __restrict__ vol, const void* __restrict__ rayo,
    const void* __restrict__ rayd, const void* __restrict__ w1b,
    const void* __restrict__ b1b, const void* __restrict__ w2b,
    const void* __restrict__ b2b, void* __restrict__ outp,
    const int* __restrict__ flag)
{
    __shared__ float wsm[4257];
    __shared__ float rgbL[RPB][SS][33];
    __shared__ float sigL[RPB][SS];
    if (*flag) render_body<true >(vol, rayo, rayd, w1b, b1b, w2b, b2b, outp, wsm, rgbL, sigL);
    else       render_body<false>(vol, rayo, rayd, w1b, b1b, w2b, b2b, outp, wsm, rgbL, sigL);
}

extern "C" void kernel_launch(void* const* d_in, const int* in_sizes, int n_in,
                              void* d_out, int out_size, void* d_ws, size_t ws_size,
                              hipStream_t stream) {
    const void* vol  = d_in[0];
    const void* rayo = d_in[1];
    const void* rayd = d_in[2];
    const void* w1   = d_in[3];
    const void* b1   = d_in[4];
    const void* w2   = d_in[5];
    const void* b2   = d_in[6];
    int* flag = (int*)d_ws;
    void* tex = (void*)((char*)d_ws + TEXOFF);

    const size_t need = TEXOFF + (size_t)6 * HH * WW * CC * 4;   // f32 worst case

    detect_dtype<<<dim3(1), dim3(64), 0, stream>>>(rayo, flag);
    if (ws_size >= need) {
        transpose_tex<<<dim3(WW / 128, HH, 6), dim3(1024), 0, stream>>>(vol, tex, flag);
        render_fast<<<dim3(NRAYS / RPB), dim3(256), 0, stream>>>(
            tex, rayo, rayd, w1, b1, w2, b2, d_out, flag);
    } else {
        render_any<<<dim3(NRAYS / RPB), dim3(256), 0, stream>>>(
            vol, rayo, rayd, w1, b1, w2, b2, d_out, flag);
    }
}

// Round 12
// 240.769 us; speedup vs baseline: 1.1258x; 1.1258x over previous
//
#include <hip/hip_runtime.h>
#include <math.h>

// Problem constants (from reference)
#define HH 256
#define WW 256
#define CC 32
#define SS 32
#define NRAYS 32768            // N*R = 2*16384
#define RPB 8                  // rays per block
#define TEXOFF 256             // byte offset of HWC bf16 texture in d_ws

// LDS pool layout (bytes, all 16-aligned)
#define FXB_OFF 0              // 256 rows x 80 B (40 ushort bf16; ch 0..31 in [0,64))
#define SIG_OFF 20480          // f32[256] raw sigma
#define WST_OFF 21504          // w1t 4096 B | w2t 6144 B; aliased by hb after frag load
#define W2T_OFF 25600
#define ALP_OFF 31744          // f32[256]: per-interval alpha -> 0.5*alpha*T weights
#define POOLSZ  32768          // exactly 32 KB -> 5 blocks/CU by LDS
// hb (per-wave h buffer, 16 rows x 144 B) aliases WST: wave w at WST_OFF + w*2304

typedef __attribute__((ext_vector_type(8))) short short8;   // 8 bf16
typedef __attribute__((ext_vector_type(4))) float f32x4;

__device__ __forceinline__ f32x4 mfma16(short8 a, short8 b, f32x4 c) {
    return __builtin_amdgcn_mfma_f32_16x16x32_bf16(a, b, c, 0, 0, 0);
}

// ---------- helpers ----------
__device__ __forceinline__ float bf2f(unsigned short u) {
    union { unsigned int ui; float f; } v; v.ui = ((unsigned int)u) << 16; return v.f;
}
__device__ __forceinline__ float lo2f(unsigned int w) {
    union { unsigned int ui; float f; } v; v.ui = w << 16; return v.f;
}
__device__ __forceinline__ float hi2f(unsigned int w) {
    union { unsigned int ui; float f; } v; v.ui = w & 0xffff0000u; return v.f;
}
__device__ __forceinline__ unsigned short f2bf(float f) {
    union { float f; unsigned int u; } v; v.f = f;
    unsigned int u = v.u;
    unsigned int r = u + 0x7fffu + ((u >> 16) & 1u);   // RNE
    return (unsigned short)(r >> 16);
}
__device__ __forceinline__ unsigned int pk_bf16(float a, float b) {
    return (unsigned int)f2bf(a) | ((unsigned int)f2bf(b) << 16);
}
__device__ __forceinline__ int iclamp(int x, int lo, int hi) {
    return x < lo ? lo : (x > hi ? hi : x);
}
__device__ __forceinline__ float softplus_f(float z) {       // precise (fallback)
    return fmaxf(z, 0.f) + log1pf(expf(-fabsf(z)));
}
__device__ __forceinline__ float softplus_fast(float z) {
    return fmaxf(z, 0.f) + __logf(1.0f + __expf(-fabsf(z)));
}
__device__ __forceinline__ float sigmoid_fast(float z) {
    return __builtin_amdgcn_rcpf(1.0f + __expf(-z));
}

template<bool F32>
__device__ __forceinline__ float ldv(const void* p, size_t i) {
    if (F32) return ((const float*)p)[i];
    else     return bf2f(((const unsigned short*)p)[i]);
}

// ---------- dtype detection: |ray_origin| == 2.7 (by construction) ----------
__global__ void detect_dtype(const void* __restrict__ rayo, int* __restrict__ flag) {
    const int t = threadIdx.x;
    float sf = 0.f, sb = 0.f;
    if (t < 8) {
        const float* f = (const float*)rayo;
        const unsigned short* u = (const unsigned short*)rayo;
        const float a = f[3 * t], b = f[3 * t + 1], c = f[3 * t + 2];
        const float nf = a * a + b * b + c * c;
        sf = fminf(fabsf(nf - 7.29f), 1e3f);            // fminf(NaN,x)=x -> NaN-safe
        const float x = bf2f(u[3 * t]), y = bf2f(u[3 * t + 1]), z = bf2f(u[3 * t + 2]);
        const float nb = x * x + y * y + z * z;
        sb = fminf(fabsf(nb - 7.29f), 1e3f);
    }
    sf += __shfl_down(sf, 4); sb += __shfl_down(sb, 4);
    sf += __shfl_down(sf, 2); sb += __shfl_down(sb, 2);
    sf += __shfl_down(sf, 1); sb += __shfl_down(sb, 1);
    if (t == 0 && blockIdx.x == 0) *flag = (sf < sb) ? 1 : 0;   // 1 = float32 inputs
}

// ---------- CHW -> HWC transpose; OUTPUT ALWAYS bf16 (halves gather traffic) ----------
__global__ __launch_bounds__(1024) void transpose_tex(
    const void* __restrict__ vol, unsigned short* __restrict__ tex,
    const int* __restrict__ flag) {
    __shared__ __align__(16) unsigned short tb[32][129];
    const int l = threadIdx.x;
    const int tx = l & 31, ty = l >> 5;    // phase 1: c = ty, w-quad = tx
    const int wq = l >> 3, cq = l & 7;     // phase 2: w = w0+wq, c-quad = cq
    const int w0 = blockIdx.x * 128;
    const int h  = blockIdx.y;
    const int img = blockIdx.z;
    const size_t srcE = (((size_t)img * CC + ty) * HH + h) * WW + w0 + 4 * tx;
    const size_t dstE = (((size_t)img * HH + h) * WW + (w0 + wq)) * CC + 4 * cq;
    if (*flag) {
        const float4 v = *(const float4*)((const float*)vol + srcE);
        tb[ty][4 * tx + 0] = f2bf(v.x); tb[ty][4 * tx + 1] = f2bf(v.y);
        tb[ty][4 * tx + 2] = f2bf(v.z); tb[ty][4 * tx + 3] = f2bf(v.w);
    } else {
        *(ushort4*)&tb[ty][4 * tx] = *(const ushort4*)((const unsigned short*)vol + srcE);
    }
    __syncthreads();
    ushort4 o;
    o.x = tb[4 * cq + 0][wq]; o.y = tb[4 * cq + 1][wq];
    o.z = tb[4 * cq + 2][wq]; o.w = tb[4 * cq + 3][wq];
    *(ushort4*)(tex + dstE) = o;
}

// ================= fast path: bf16 gather + MFMA MLP + split marcher =================
template<bool F32>
__device__ void render_mfma_body(
    const unsigned short* __restrict__ tex,   // [6][256][256][32] bf16 HWC
    const void* __restrict__ rayo, const void* __restrict__ rayd,
    const void* __restrict__ w1b, const void* __restrict__ b1b,
    const void* __restrict__ w2b, const void* __restrict__ b2b,
    void* __restrict__ outp, char* __restrict__ pool)
{
    const int t = threadIdx.x;
    unsigned short* fxB = (unsigned short*)(pool + FXB_OFF);   // stride 40 ushort/row
    float* sigL = (float*)(pool + SIG_OFF);
    unsigned short* w1t = (unsigned short*)(pool + WST_OFF);   // [n<64][k<32]
    unsigned short* w2t = (unsigned short*)(pool + W2T_OFF);   // [n<48][k<64]
    float* aL = (float*)(pool + ALP_OFF);                      // alpha -> weights

    // ---- stage weights: LINEAR LDS writes (conflict-free); transpose in the
    //      global read index (one-time 8/16 KB, L2-absorbed) ----
    for (int i = t; i < 2048; i += 256) {        // w1t[i], layout [n][k] stride 32
        const int n = i >> 5, k = i & 31;
        w1t[i] = f2bf(ldv<F32>(w1b, (size_t)k * 64 + n));
    }
    for (int i = t; i < 3072; i += 256) {        // w2t[i], layout [n][k] stride 64
        const int n = i >> 6, k = i & 63;
        w2t[i] = (n < 33) ? f2bf(ldv<F32>(w2b, (size_t)k * 33 + n)) : (unsigned short)0;
    }
    __syncthreads();

    // ---- gather: 8-lane sub-group per (ray, sample-subset); lane = 4 channels ----
    {
        const int rl = t >> 5;                 // ray in block
        const int L  = t & 31;
        const int c4 = L & 7;                  // channel quad: ch 4*c4..4*c4+3
        const int sub = L >> 3;                // sample subset 0..3
        const int gray = blockIdx.x * RPB + rl;
        const int n = gray >> 14;
        const size_t rb = (size_t)gray * 3;
        const float ox = ldv<F32>(rayo, rb), oy = ldv<F32>(rayo, rb + 1), oz = ldv<F32>(rayo, rb + 2);
        const float dx = ldv<F32>(rayd, rb), dy = ldv<F32>(rayd, rb + 1), dz = ldv<F32>(rayd, rb + 2);
        const char* texb = (const char*)tex;
        const unsigned int cb = (unsigned int)c4 * 8;   // byte offset of channel quad

        #pragma unroll 2
        for (int k = 0; k < 8; ++k) {
            const int s = sub * 8 + k;
            const float d = 2.25f + 1.05f * ((s + 0.5f) * (1.0f / 32.0f));
            const float x = (ox + d * dx) * 2.0f;
            const float y = (oy + d * dy) * 2.0f;
            const float z = (oz + d * dz) * 2.0f;
            float a0[4] = {0.f, 0.f, 0.f, 0.f};
            float a1[4] = {0.f, 0.f, 0.f, 0.f};
            float a2[4] = {0.f, 0.f, 0.f, 0.f};
            #pragma unroll
            for (int p = 0; p < 3; p++) {
                // p0:(x,y)  p1:(y,z)  p2:(x,z)
                const float u = (p == 0) ? x : ((p == 1) ? y : x);
                const float v = (p == 0) ? y : z;
                const float ixf = fmaf(u, 127.5f, 127.5f);
                const float iyf = fmaf(v, 127.5f, 127.5f);
                const float ix0f = floorf(ixf), iy0f = floorf(iyf);
                const float wx1 = ixf - ix0f, wy1 = iyf - iy0f;
                const float wx0 = 1.f - wx1,  wy0 = 1.f - wy1;
                const int ix0 = iclamp((int)ix0f, 0, 255);
                const int ix1 = iclamp((int)ix0f + 1, 0, 255);
                const int iy0 = iclamp((int)iy0f, 0, 255);
                const int iy1 = iclamp((int)iy0f + 1, 0, 255);
                const float w00 = wx0 * wy0, w01 = wx1 * wy0, w10 = wx0 * wy1, w11 = wx1 * wy1;
                const unsigned int pb = (unsigned int)(n * 3 + p) * (HH * WW * CC * 2) + cb;
                // one dwordx2 load per corner: 4 bf16 channels
                const uint2 q00 = *(const uint2*)(texb + pb + ((unsigned int)(iy0 * WW + ix0) << 6));
                const uint2 q01 = *(const uint2*)(texb + pb + ((unsigned int)(iy0 * WW + ix1) << 6));
                const uint2 q10 = *(const uint2*)(texb + pb + ((unsigned int)(iy1 * WW + ix0) << 6));
                const uint2 q11 = *(const uint2*)(texb + pb + ((unsigned int)(iy1 * WW + ix1) << 6));
                const float v00[4] = { lo2f(q00.x), hi2f(q00.x), lo2f(q00.y), hi2f(q00.y) };
                const float v01[4] = { lo2f(q01.x), hi2f(q01.x), lo2f(q01.y), hi2f(q01.y) };
                const float v10[4] = { lo2f(q10.x), hi2f(q10.x), lo2f(q10.y), hi2f(q10.y) };
                const float v11[4] = { lo2f(q11.x), hi2f(q11.x), lo2f(q11.y), hi2f(q11.y) };
                #pragma unroll
                for (int i = 0; i < 4; i++) {
                    float acc = w00 * v00[i];
                    acc = fmaf(w01, v01[i], acc);
                    acc = fmaf(w10, v10[i], acc);
                    acc = fmaf(w11, v11[i], acc);
                    if (p == 0) a0[i] = acc; else if (p == 1) a1[i] = acc; else a2[i] = acc;
                }
            }
            // pack 4 bf16 channels, single 8-B LDS write
            uint2 pk;
            pk.x = pk_bf16((a0[0] + a1[0] + a2[0]) * (1.0f / 3.0f),
                           (a0[1] + a1[1] + a2[1]) * (1.0f / 3.0f));
            pk.y = pk_bf16((a0[2] + a1[2] + a2[2]) * (1.0f / 3.0f),
                           (a0[3] + a1[3] + a2[3]) * (1.0f / 3.0f));
            *(uint2*)(pool + FXB_OFF + (rl * 32 + s) * 80 + c4 * 8) = pk;
        }
    }

    // ---- load B fragments to registers (w1t/w2t LDS dies after this) ----
    const int w = t >> 6;
    const int lane = t & 63;
    const int l16 = lane & 15, quad = lane >> 4;

    short8 b1f[4];
    #pragma unroll
    for (int nt = 0; nt < 4; nt++)
        b1f[nt] = *(const short8*)(pool + WST_OFF + (nt * 16 + l16) * 64 + quad * 16);
    short8 b2f[3][2];
    #pragma unroll
    for (int nt = 0; nt < 3; nt++)
        #pragma unroll
        for (int ks = 0; ks < 2; ks++)
            b2f[nt][ks] = *(const short8*)(pool + W2T_OFF + (nt * 16 + l16) * 128 + ks * 64 + quad * 16);
    float bb1[4], bb2[3];
    #pragma unroll
    for (int nt = 0; nt < 4; nt++) bb1[nt] = ldv<F32>(b1b, nt * 16 + l16);
    #pragma unroll
    for (int nt = 0; nt < 3; nt++) {
        const int n2 = nt * 16 + l16;
        bb2[nt] = (n2 < 33) ? ldv<F32>(b2b, n2) : 0.f;
    }
    __syncthreads();   // fxB ready; all waves done reading w1t/w2t (hb aliases it)

    // ---- MFMA MLP: wave w owns sample rows [64w, 64w+64) ----
    {
        char* hb = pool + WST_OFF + w * 2304;    // 16 rows x 144 B
        #pragma unroll 1
        for (int mt = 0; mt < 4; mt++) {
            const int rbase = w * 64 + mt * 16;
            const short8 a1 = *(const short8*)(pool + FXB_OFF + (rbase + l16) * 80 + quad * 16);
            #pragma unroll
            for (int nt = 0; nt < 4; nt++) {
                f32x4 hc = { bb1[nt], bb1[nt], bb1[nt], bb1[nt] };
                hc = mfma16(a1, b1f[nt], hc);
                #pragma unroll
                for (int r = 0; r < 4; r++) {
                    const float hv = softplus_fast(hc[r]);
                    *(unsigned short*)(hb + (quad * 4 + r) * 144 + (nt * 16 + l16) * 2) = f2bf(hv);
                }
            }
            const short8 a2k0 = *(const short8*)(hb + l16 * 144 + quad * 16);
            const short8 a2k1 = *(const short8*)(hb + l16 * 144 + 64 + quad * 16);
            #pragma unroll
            for (int nt = 0; nt < 3; nt++) {
                f32x4 o = { bb2[nt], bb2[nt], bb2[nt], bb2[nt] };
                o = mfma16(a2k0, b2f[nt][0], o);
                o = mfma16(a2k1, b2f[nt][1], o);
                #pragma unroll
                for (int r = 0; r < 4; r++) {
                    const int row = rbase + quad * 4 + r;
                    if (nt == 0) {
                        if (l16 == 0) sigL[row] = o[r];                      // raw sigma (n=0)
                        else fxB[row * 40 + (l16 - 1)] =
                                 f2bf(fmaf(sigmoid_fast(o[r]), 1.002f, -0.001f));   // ch 0..14
                    } else if (nt == 1) {
                        fxB[row * 40 + (15 + l16)] =
                                 f2bf(fmaf(sigmoid_fast(o[r]), 1.002f, -0.001f));   // ch 15..30
                    } else if (l16 == 0) {
                        fxB[row * 40 + 31] =
                                 f2bf(fmaf(sigmoid_fast(o[r]), 1.002f, -0.001f));   // ch 31
                    }
                }
            }
        }
    }
    __syncthreads();

    // ---- marcher phase 1: thread t = (ray rl, interval sm) computes alpha once ----
    {
        const int rl = t >> 5, sm = t & 31;
        if (sm < 31) {
            const float sp = sigL[rl * 32 + sm];
            const float sn = sigL[rl * 32 + sm + 1];
            const float m = 0.5f * (sp + sn) - 1.0f;
            const float dens = fmaxf(m, 0.f) + __logf(1.0f + __expf(-fabsf(m)));
            aL[rl * 32 + sm] = 1.0f - __expf(-(1.05f / 32.0f) * dens);
        }
    }
    __syncthreads();

    // ---- marcher phase 2: one lane per ray does the serial T-scan -> 0.5*alpha*T ----
    {
        const int rl = t >> 5, sm = t & 31;
        if (sm == 0) {
            float T = 1.0f;
            #pragma unroll
            for (int j = 0; j < 31; j++) {
                const float a = aL[rl * 32 + j];
                aL[rl * 32 + j] = (a * T) * 0.5f;
                T *= (1.0f - a + 1e-10f);
            }
        }
    }
    __syncthreads();

    // ---- marcher phase 3: pure FMA channel walk ----
    {
        const int rl = t >> 5, c = t & 31;
        const int gr2 = blockIdx.x * RPB + rl;
        float acc = 0.0f;
        float rp = bf2f(fxB[(rl * 32 + 0) * 40 + c]);
        #pragma unroll 4
        for (int sm = 0; sm < 31; sm++) {
            const float rn = bf2f(fxB[(rl * 32 + sm + 1) * 40 + c]);
            acc = fmaf(aL[rl * 32 + sm], rp + rn, acc);
            rp = rn;
        }
        const size_t oidx = (size_t)gr2 * 32 + c;
        if (F32) ((float*)outp)[oidx] = acc;
        else     ((unsigned short*)outp)[oidx] = f2bf(acc);
    }
}

__global__ __launch_bounds__(256, 4) void render_fast(
    const unsigned short* __restrict__ tex, const void* __restrict__ rayo,
    const void* __restrict__ rayd, const void* __restrict__ w1b,
    const void* __restrict__ b1b, const void* __restrict__ w2b,
    const void* __restrict__ b2b, void* __restrict__ outp,
    const int* __restrict__ flag)
{
    __shared__ __align__(16) char pool[POOLSZ];
    if (*flag) render_mfma_body<true >(tex, rayo, rayd, w1b, b1b, w2b, b2b, outp, pool);
    else       render_mfma_body<false>(tex, rayo, rayd, w1b, b1b, w2b, b2b, outp, pool);
}

// ================= no-workspace fallback (round-3 verified) =================
template<bool F32>
__device__ __forceinline__ void render_body(
    const void* __restrict__ vol, const void* __restrict__ rayo,
    const void* __restrict__ rayd, const void* __restrict__ w1b,
    const void* __restrict__ b1b, const void* __restrict__ w2b,
    const void* __restrict__ b2b, void* __restrict__ outp,
    float* wsm, float (*rgbL)[SS][33], float (*sigL)[SS])
{
    const int t = threadIdx.x;
    for (int i = t; i < 4257; i += 256) {
        float v;
        if (i < 2048)       v = ldv<F32>(w1b, i);
        else if (i < 2112)  v = ldv<F32>(b1b, i - 2048);
        else if (i < 4224)  v = ldv<F32>(w2b, i - 2112);
        else                v = ldv<F32>(b2b, i - 4224);
        wsm[i] = v;
    }
    __syncthreads();

    const int rl = t >> 5;
    const int s  = t & 31;
    const int gray = blockIdx.x * RPB + rl;
    const int n = gray >> 14;

    const size_t rbase = (size_t)gray * 3;
    const float ox = ldv<F32>(rayo, rbase), oy = ldv<F32>(rayo, rbase + 1), oz = ldv<F32>(rayo, rbase + 2);
    const float dx = ldv<F32>(rayd, rbase), dy = ldv<F32>(rayd, rbase + 1), dz = ldv<F32>(rayd, rbase + 2);
    const float d = 2.25f + 1.05f * ((s + 0.5f) * (1.0f / 32.0f));
    const float x = (ox + d * dx) * 2.0f;
    const float y = (oy + d * dy) * 2.0f;
    const float z = (oz + d * dz) * 2.0f;

    float fx[32];
    #pragma unroll
    for (int c = 0; c < 32; c++) fx[c] = 0.f;

    #pragma unroll
    for (int p = 0; p < 3; p++) {
        const float u = (p == 0) ? x : ((p == 1) ? y : x);
        const float v = (p == 0) ? y : z;
        const float ixf = fmaf(u, 127.5f, 127.5f);
        const float iyf = fmaf(v, 127.5f, 127.5f);
        const float ix0f = floorf(ixf), iy0f = floorf(iyf);
        const float wx1 = ixf - ix0f, wy1 = iyf - iy0f;
        const float wx0 = 1.f - wx1,  wy0 = 1.f - wy1;
        const int ix0 = iclamp((int)ix0f, 0, 255);
        const int ix1 = iclamp((int)ix0f + 1, 0, 255);
        const int iy0 = iclamp((int)iy0f, 0, 255);
        const int iy1 = iclamp((int)iy0f + 1, 0, 255);
        const float wnw = wx0 * wy0, wne = wx1 * wy0, wsw = wx0 * wy1, wse = wx1 * wy1;
        const int i00 = iy0 * WW + ix0, i01 = iy0 * WW + ix1;
        const int i10 = iy1 * WW + ix0, i11 = iy1 * WW + ix1;
        const size_t pb = (size_t)(n * 3 + p) * CC * HH * WW;
        #pragma unroll
        for (int c = 0; c < 32; c++) {
            const size_t cb = pb + (size_t)c * (HH * WW);
            fx[c] += wnw * ldv<F32>(vol, cb + i00) + wne * ldv<F32>(vol, cb + i01)
                   + wsw * ldv<F32>(vol, cb + i10) + wse * ldv<F32>(vol, cb + i11);
        }
    }
    #pragma unroll
    for (int c = 0; c < 32; c++) fx[c] *= (1.0f / 3.0f);

    const float* W1 = wsm;
    const float* B1 = wsm + 2048;
    const float* W2 = wsm + 2112;
    const float* B2 = wsm + 4224;

    float h[64];
    #pragma unroll
    for (int j = 0; j < 64; j++) h[j] = B1[j];
    #pragma unroll
    for (int c = 0; c < 32; c++) {
        const float f = fx[c];
        #pragma unroll
        for (int j = 0; j < 64; j++) h[j] = fmaf(f, W1[c * 64 + j], h[j]);
    }
    #pragma unroll
    for (int j = 0; j < 64; j++) h[j] = softplus_f(h[j]);

    #pragma unroll 1
    for (int k = 0; k < 33; k++) {
        float zz = B2[k];
        #pragma unroll
        for (int j = 0; j < 64; j++) zz = fmaf(h[j], W2[j * 33 + k], zz);
        if (k == 0) sigL[rl][s] = zz;
        else {
            const float sg = 1.0f / (1.0f + expf(-zz));
            rgbL[rl][s][k - 1] = fmaf(sg, 1.002f, -0.001f);
        }
    }
    __syncthreads();

    const int c = t & 31;
    const float delta = 1.05f / 32.0f;
    float T = 1.0f, acc = 0.0f;
    float sig_prev = sigL[rl][0];
    float rgb_prev = rgbL[rl][0][c];
    #pragma unroll 1
    for (int sm = 0; sm < 31; sm++) {
        const float sig_next = sigL[rl][sm + 1];
        const float rgb_next = rgbL[rl][sm + 1][c];
        const float dens = softplus_f(0.5f * (sig_prev + sig_next) - 1.0f);
        const float alpha = 1.0f - expf(-delta * dens);
        acc += alpha * T * 0.5f * (rgb_prev + rgb_next);
        T *= (1.0f - alpha + 1e-10f);
        sig_prev = sig_next;
        rgb_prev = rgb_next;
    }
    const size_t oidx = (size_t)gray * 32 + c;
    if (F32) ((float*)outp)[oidx] = acc;
    else     ((unsigned short*)outp)[oidx] = f2bf(acc);
}

__global__ __launch_bounds__(256) void render_any(
    const void* __restrict__ vol, const void* __restrict__ rayo,
    const void* __restrict__ rayd, const void* __restrict__ w1b,
    const void* __restrict__ b1b, const void* __restrict__ w2b,
    const void* __restrict__ b2b, void* __restrict__ outp,
    const int* __restrict__ flag)
{
    __shared__ float wsm[4257];
    __shared__ float rgbL[RPB][SS][33];
    __shared__ float sigL[RPB][SS];
    if (*flag) render_body<true >(vol, rayo, rayd, w1b, b1b, w2b, b2b, outp, wsm, rgbL, sigL);
    else       render_body<false>(vol, rayo, rayd, w1b, b1b, w2b, b2b, outp, wsm, rgbL, sigL);
}

extern "C" void kernel_launch(void* const* d_in, const int* in_sizes, int n_in,
                              void* d_out, int out_size, void* d_ws, size_t ws_size,
                              hipStream_t stream) {
    const void* vol  = d_in[0];
    const void* rayo = d_in[1];
    const void* rayd = d_in[2];
    const void* w1   = d_in[3];
    const void* b1   = d_in[4];
    const void* w2   = d_in[5];
    const void* b2   = d_in[6];
    int* flag = (int*)d_ws;
    unsigned short* tex = (unsigned short*)((char*)d_ws + TEXOFF);

    const size_t need = TEXOFF + (size_t)6 * HH * WW * CC * 2;   // bf16 texture always

    detect_dtype<<<dim3(1), dim3(64), 0, stream>>>(rayo, flag);
    if (ws_size >= need) {
        transpose_tex<<<dim3(WW / 128, HH, 6), dim3(1024), 0, stream>>>(vol, tex, flag);
        render_fast<<<dim3(NRAYS / RPB), dim3(256), 0, stream>>>(
            tex, rayo, rayd, w1, b1, w2, b2, d_out, flag);
    } else {
        render_any<<<dim3(NRAYS / RPB), dim3(256), 0, stream>>>(
            vol, rayo, rayd, w1, b1, w2, b2, d_out, flag);
    }
}